// Round 5
// baseline (3658.327 us; speedup 1.0000x reference)
//
#include <hip/hip_runtime.h>
#include <math.h>

#define NTHREADS 512
#define NPTS 2048
#define MSTEPS (NPTS / 64)              // 32
#define RPW 4                           // rows per wave
#define NWAVES (NTHREADS / 64)          // 8
#define ROWS_PER_BLOCK (NWAVES * RPW)   // 32
#define BLKB (NPTS / ROWS_PER_BLOCK)    // 64 blocks per batch
#define BATCH 8
#define NBLOCKS (BATCH * BLKB)          // 512
#define SINK_ITERS 20

#if __has_builtin(__builtin_amdgcn_exp2f)
#define EXP2(x) __builtin_amdgcn_exp2f(x)
#else
#define EXP2(x) exp2f(x)
#endif

// ---------- workspace layout (bytes) ----------
//   [0]        float acc            (own 128B line)
//   [128]      uint  done           (own 128B line)
//   [1024 + b*512]        uint arrive[b]   (own 256B line)
//   [1024 + b*512 + 256]  uint rel[b]      (own 256B line, poll-only)
//   [8192]               float F[8][2048]   (64 KB)
//   [8192 + 64K]         float G[8][2048]   (64 KB)
//   [8192 + 128K]        uint  CMIN[8][2048](64 KB)  -- memset 0x7f
#define WS_BAR   1024
#define WS_F     8192
#define WS_G     (WS_F + 4 * BATCH * NPTS)
#define WS_CMIN  (WS_F + 8 * BATCH * NPTS)

static __device__ __forceinline__ float aload(const float* p) {
  return __hip_atomic_load(p, __ATOMIC_RELAXED, __HIP_MEMORY_SCOPE_AGENT);
}
static __device__ __forceinline__ unsigned aloadu(const unsigned* p) {
  return __hip_atomic_load(p, __ATOMIC_RELAXED, __HIP_MEMORY_SCOPE_AGENT);
}
static __device__ __forceinline__ void astore(float* p, float v) {
  __hip_atomic_store(p, v, __ATOMIC_RELAXED, __HIP_MEMORY_SCOPE_AGENT);
}

__global__ void __launch_bounds__(NTHREADS, 4)
sinkhorn_loss_kernel(const float* __restrict__ target,
                     const float* __restrict__ pre,
                     float* __restrict__ out,
                     unsigned char* __restrict__ ws)
{
  float*    acc    = (float*)ws;
  unsigned* done   = (unsigned*)(ws + 128);
  float*    F      = (float*)(ws + WS_F);
  float*    G      = (float*)(ws + WS_G);
  unsigned* CMIN   = (unsigned*)(ws + WS_CMIN);

  // Points live in LDS for the whole kernel, pre-scaled: {x*S1, y*S1, z*S1, yy}
  __shared__ float4 ptsT[NPTS];     // 32 KB (columns for F-update / chamfer)
  __shared__ float4 ptsP[NPTS];     // 32 KB
  __shared__ float  Vw[NPTS];       // 8 KB  (per-pass column potential / colmin)
  __shared__ float  blockAcc;

  const int tid  = threadIdx.x;
  const int wid  = tid >> 6;
  const int lane = tid & 63;
  const int b    = blockIdx.x / BLKB;
  const int bib  = blockIdx.x % BLKB;

  const float S2  = 7.21347520444482f;   // 1/(EPS*ln2)
  const float S1  = sqrtf(S2);
  const float LB2 = -11.0f;              // log2(1/2048)

  const float* tb = target + (size_t)b * NPTS * 3;
  const float* pb = pre    + (size_t)b * NPTS * 3;
  float*    Fb  = F    + b * NPTS;
  float*    Gb  = G    + b * NPTS;
  unsigned* CMb = CMIN + b * NPTS;
  unsigned* arrive = (unsigned*)(ws + WS_BAR + b * 512);
  unsigned* rel    = (unsigned*)(ws + WS_BAR + b * 512 + 256);

  int gen = 0;

  // ---- per-batch barrier: RMW on `arrive`, poll read-only `rel` ----
  auto gbar = [&]() {
    ++gen;
    __syncthreads();
    if (tid == 0) {
      __threadfence();
      unsigned old = __hip_atomic_fetch_add(arrive, 1u, __ATOMIC_ACQ_REL,
                                            __HIP_MEMORY_SCOPE_AGENT);
      if (old == (unsigned)(gen * BLKB) - 1u) {
        __hip_atomic_store(rel, (unsigned)gen, __ATOMIC_RELEASE,
                           __HIP_MEMORY_SCOPE_AGENT);
      } else {
        while (__hip_atomic_load(rel, __ATOMIC_ACQUIRE,
                                 __HIP_MEMORY_SCOPE_AGENT) < (unsigned)gen)
          __builtin_amdgcn_s_sleep(8);
      }
      __threadfence();
    }
    __syncthreads();
  };

  // ---- stage points into LDS once ----
  for (int m = tid; m < NPTS; m += NTHREADS) {
    const float* p = tb + m * 3;
    float y0 = p[0] * S1, y1 = p[1] * S1, y2 = p[2] * S1;
    ptsT[m] = make_float4(y0, y1, y2, y0 * y0 + y1 * y1 + y2 * y2);
    const float* q = pb + m * 3;
    float z0 = q[0] * S1, z1 = q[1] * S1, z2 = q[2] * S1;
    ptsP[m] = make_float4(z0, z1, z2, z0 * z0 + z1 * z1 + z2 * z2);
  }
  if (tid == 0) blockAcc = 0.0f;

  const int n0 = bib * ROWS_PER_BLOCK + wid * RPW;

  // rows from LDS (float4 {sx,sy,sz,yy}): x2 = 2*coords, XX = yy
  auto load_rows = [&](const float4* pts, float x2[RPW][3], float XX[RPW]) {
#pragma unroll
    for (int r = 0; r < RPW; ++r) {
      float4 a = pts[n0 + r];
      XX[r] = a.w;
      x2[r][0] = a.x + a.x; x2[r][1] = a.y + a.y; x2[r][2] = a.z + a.z;
    }
  };

  // ================= Chamfer pass =================
  __syncthreads();
  for (int m = tid; m < NPTS; m += NTHREADS)
    ((unsigned*)Vw)[m] = 0x7f800000u;             // +inf colmin
  __syncthreads();
  {
    float x2[RPW][3], XX[RPW], rmax[RPW];
    load_rows(ptsP, x2, XX);
#pragma unroll
    for (int r = 0; r < RPW; ++r) rmax[r] = -3.0e38f;
    for (int ms = 0; ms < MSTEPS; ++ms) {
      float4 v = ptsT[ms * 64 + lane];
      float cmin = 3.0e38f;
#pragma unroll
      for (int r = 0; r < RPW; ++r) {
        float t = -v.w;                           // -YY
        t = fmaf(x2[r][0], v.x, t);
        t = fmaf(x2[r][1], v.y, t);
        t = fmaf(x2[r][2], v.z, t);               // t = 2xy - YY
        rmax[r] = fmaxf(rmax[r], t);
        cmin = fminf(cmin, XX[r] - t);            // C2 = XX + YY - 2xy
      }
      atomicMin((unsigned*)&Vw[ms * 64 + lane], __float_as_uint(cmin));
    }
    float d1sum = 0.0f;
#pragma unroll
    for (int r = 0; r < RPW; ++r) {
      float t = rmax[r];
      for (int off = 32; off; off >>= 1) t = fmaxf(t, __shfl_xor(t, off));
      d1sum += XX[r] - t;                         // min_m C2 (weight 1.0)
    }
    if (lane == 0) atomicAdd(&blockAcc, d1sum);   // LDS atomic — cheap
    __syncthreads();
    for (int m = tid; m < NPTS; m += NTHREADS)
      atomicMin(&CMb[m], ((unsigned*)Vw)[m]);     // spread addresses, low contention
  }
  gbar();  // gen 1: CMIN complete for this batch
  if (wid == 0 && lane < 32) {                    // this block's 32 columns
    float d2 = __uint_as_float(aloadu(&CMb[bib * ROWS_PER_BLOCK + lane]));
#pragma unroll
    for (int off = 16; off; off >>= 1) d2 += __shfl_xor(d2, off);
    if (lane == 0) atomicAdd(&blockAcc, 0.5f * d2);
  }

  // ================= Sinkhorn: 20 x (F-update, G-update) =================
  auto build_vw = [&](const float4* pts, const float* V, float addc) {
    for (int m = tid; m < NPTS; m += NTHREADS)
      Vw[m] = aload(V + m) - pts[m].w + addc;     // V - YY + addc
  };

  auto sink_pass = [&](const float4* rowpts, const float4* colpts, float* Vout) {
    float x2[RPW][3], XX[RPW], S[RPW];
    load_rows(rowpts, x2, XX);
#pragma unroll
    for (int r = 0; r < RPW; ++r) S[r] = 0.0f;
    for (int ms = 0; ms < MSTEPS; ++ms) {
      float4 v = colpts[ms * 64 + lane];
      float  w = Vw[ms * 64 + lane];
#pragma unroll
      for (int r = 0; r < RPW; ++r) {
        float t = w - XX[r];
        t = fmaf(x2[r][0], v.x, t);
        t = fmaf(x2[r][1], v.y, t);
        t = fmaf(x2[r][2], v.z, t);               // t = V - C2 + lb2 (log2 dom)
        S[r] += EXP2(t);
      }
    }
#pragma unroll
    for (int r = 0; r < RPW; ++r) {
      float s = S[r];
      for (int off = 32; off; off >>= 1) s += __shfl_xor(s, off);
      if (lane == r) astore(Vout + n0 + r, -log2f(s));
    }
  };

  for (int it = 0; it < SINK_ITERS; ++it) {
    build_vw(ptsT, Gb, LB2);                      // G zeroed by memset for it==0
    __syncthreads();
    sink_pass(ptsP, ptsT, Fb);
    gbar();
    build_vw(ptsP, Fb, LB2);
    __syncthreads();
    sink_pass(ptsT, ptsP, Gb);
    gbar();
  }

  // ================= Final transport-cost pass =================
  for (int m = tid; m < NPTS; m += NTHREADS)
    Vw[m] = aload(Gb + m);                        // raw G
  __syncthreads();
  {
    float x2[RPW][3], XX[RPW], A2[RPW], Ar[RPW], Sf[RPW];
    load_rows(ptsP, x2, XX);
#pragma unroll
    for (int r = 0; r < RPW; ++r) {
      A2[r] = aload(Fb + n0 + r);                 // F[n]
      Ar[r] = A2[r] - XX[r];
      Sf[r] = 0.0f;
    }
    for (int ms = 0; ms < MSTEPS; ++ms) {
      float4 v = ptsT[ms * 64 + lane];
      float  g = Vw[ms * 64 + lane];
      float  base = g - v.w;                      // G - YY
#pragma unroll
      for (int r = 0; r < RPW; ++r) {
        float u = base + Ar[r];                   // F + G - C2 (log2 dom)
        u = fmaf(x2[r][0], v.x, u);
        u = fmaf(x2[r][1], v.y, u);
        u = fmaf(x2[r][2], v.z, u);
        float e  = EXP2(u);
        float c2 = (A2[r] - u) + g;               // C2 = F + G - u
        Sf[r] = fmaf(e, c2, Sf[r]);
      }
    }
    float tot = 0.0f;
#pragma unroll
    for (int r = 0; r < RPW; ++r) {
      float s = Sf[r];
      for (int off = 32; off; off >>= 1) s += __shfl_xor(s, off);
      tot += s;
    }
    if (lane == 0) atomicAdd(&blockAcc, tot);
  }

  // ================= finish: one global add per block, last block writes out =====
  __syncthreads();
  if (tid == 0) {
    atomicAdd(acc, blockAcc);                     // 512 RMWs total
    __threadfence();
    unsigned old = __hip_atomic_fetch_add(done, 1u, __ATOMIC_ACQ_REL,
                                          __HIP_MEMORY_SCOPE_AGENT);
    if (old == (unsigned)NBLOCKS - 1u) {
      __threadfence();
      // out = (EPS*ln2 / 2048) * [ sum d1 + 0.5 sum d2 + sum 2^u * C2 ]
      out[0] = aload(acc) * (0.13862943611198906f / 2048.0f);
    }
  }
}

extern "C" void kernel_launch(void* const* d_in, const int* in_sizes, int n_in,
                              void* d_out, int out_size, void* d_ws, size_t ws_size,
                              hipStream_t stream) {
  const float* target = (const float*)d_in[0];
  const float* pre    = (const float*)d_in[1];
  float* out = (float*)d_out;
  unsigned char* ws = (unsigned char*)d_ws;

  // zero: acc/done/barriers + F + G ; CMIN = 0x7f7f7f7f (big positive float)
  hipMemsetAsync(ws, 0, WS_CMIN, stream);
  hipMemsetAsync(ws + WS_CMIN, 0x7f, (size_t)4 * BATCH * NPTS, stream);
  sinkhorn_loss_kernel<<<dim3(NBLOCKS), dim3(NTHREADS), 0, stream>>>(target, pre, out, ws);
}

// Round 6
// 921.800 us; speedup vs baseline: 3.9687x; 3.9687x over previous
//
#include <hip/hip_runtime.h>
#include <math.h>

#define NTHREADS 512
#define NPTS 2048
#define MSTEPS (NPTS / 64)              // 32
#define RPW 4                           // rows per wave
#define NWAVES (NTHREADS / 64)          // 8
#define ROWS_PER_BLOCK (NWAVES * RPW)   // 32
#define BLKB (NPTS / ROWS_PER_BLOCK)    // 64 blocks per batch
#define BATCH 8
#define NBLOCKS (BATCH * BLKB)          // 512
#define SINK_ITERS 20

#if __has_builtin(__builtin_amdgcn_exp2f)
#define EXP2(x) __builtin_amdgcn_exp2f(x)
#else
#define EXP2(x) exp2f(x)
#endif

// log2-domain scaling: distances scaled by S2 = 1/(EPS*ln2); coords by S1=sqrt(S2)
#define S2F 7.21347520444482f
#define LB2 -11.0f                      // log2(1/2048)

// ---------- workspace layout (bytes) ----------
//   [0]      float partial[512]                 (2 KB; chamfer d1 then += emd)
//   [4096]   float F[8][2048]                   (64 KB)
//   [4096+64K]  float G[8][2048]                (64 KB)
//   [4096+128K] uint/float CMIN[8][2048]        (64 KB) -- memset 0x7f
#define WS_PART  0
#define WS_F     4096
#define WS_G     (WS_F + 4 * BATCH * NPTS)
#define WS_CMIN  (WS_F + 8 * BATCH * NPTS)

// ================= chamfer =================
// per block: rows = 32 pre-points of one batch; cols = all 2048 target points.
// d1 (row-min) -> partial[blk]; strip col-min -> atomicMin CMIN (spread addrs).
__global__ void __launch_bounds__(NTHREADS, 4)
chamfer_kernel(const float* __restrict__ target,
               const float* __restrict__ pre,
               unsigned char* __restrict__ ws)
{
  float*    partial = (float*)(ws + WS_PART);
  unsigned* CMIN    = (unsigned*)(ws + WS_CMIN);

  __shared__ float4 cols4[NPTS];   // {sx, sy, sz, -yy}
  __shared__ float  colmin[NPTS];
  __shared__ float  wsum[NWAVES];

  const int tid  = threadIdx.x;
  const int wid  = tid >> 6;
  const int lane = tid & 63;
  const int b    = blockIdx.x / BLKB;
  const int bib  = blockIdx.x % BLKB;
  const float S1 = sqrtf(S2F);

  const float* tb = target + (size_t)b * NPTS * 3;
  const float* pb = pre    + (size_t)b * NPTS * 3;
  unsigned* CMb = CMIN + b * NPTS;

  for (int m = tid; m < NPTS; m += NTHREADS) {
    const float* p = tb + m * 3;
    float y0 = p[0] * S1, y1 = p[1] * S1, y2 = p[2] * S1;
    cols4[m] = make_float4(y0, y1, y2, -(y0 * y0 + y1 * y1 + y2 * y2));
    ((unsigned*)colmin)[m] = 0x7f800000u;   // +inf
  }
  __syncthreads();

  const int n0 = bib * ROWS_PER_BLOCK + wid * RPW;
  float x2[RPW][3], XX[RPW], rmax[RPW];
#pragma unroll
  for (int r = 0; r < RPW; ++r) {
    const float* p = pb + (n0 + r) * 3;
    float a0 = p[0] * S1, a1 = p[1] * S1, a2 = p[2] * S1;
    XX[r] = a0 * a0 + a1 * a1 + a2 * a2;
    x2[r][0] = a0 + a0; x2[r][1] = a1 + a1; x2[r][2] = a2 + a2;
    rmax[r] = -3.0e38f;
  }
  for (int ms = 0; ms < MSTEPS; ++ms) {
    float4 v = cols4[ms * 64 + lane];
    float cmin = 3.0e38f;
#pragma unroll
    for (int r = 0; r < RPW; ++r) {
      float t = v.w;                         // -YY
      t = fmaf(x2[r][0], v.x, t);
      t = fmaf(x2[r][1], v.y, t);
      t = fmaf(x2[r][2], v.z, t);            // 2xy - YY
      rmax[r] = fmaxf(rmax[r], t);
      cmin = fminf(cmin, XX[r] - t);         // C2
    }
    atomicMin((unsigned*)&colmin[ms * 64 + lane], __float_as_uint(cmin));
  }
  float d1sum = 0.0f;
#pragma unroll
  for (int r = 0; r < RPW; ++r) {
    float t = rmax[r];
    for (int off = 32; off; off >>= 1) t = fmaxf(t, __shfl_xor(t, off));
    d1sum += XX[r] - t;                      // min_m C2
  }
  if (lane == 0) wsum[wid] = d1sum;
  __syncthreads();
  if (tid == 0) {
    float s = 0.0f;
#pragma unroll
    for (int w = 0; w < NWAVES; ++w) s += wsum[w];
    partial[blockIdx.x] = s;                 // plain store, own slot
  }
  for (int m = tid; m < NPTS; m += NTHREADS)
    atomicMin(&CMb[m], ((unsigned*)colmin)[m]);
}

// ================= one Sinkhorn half-pass =================
// Vout[n] = -log2( sum_m 2^( Vin[m] - C2(n,m) + LB2 ) ), all in scaled log2 domain.
__global__ void __launch_bounds__(NTHREADS, 4)
sink_pass_kernel(const float* __restrict__ rowpts,
                 const float* __restrict__ colpts,
                 const float* __restrict__ Vin,
                 float* __restrict__ Vout)
{
  __shared__ float4 cols4[NPTS];   // {sx, sy, sz, Vin - yy + LB2}

  const int tid  = threadIdx.x;
  const int wid  = tid >> 6;
  const int lane = tid & 63;
  const int b    = blockIdx.x / BLKB;
  const int bib  = blockIdx.x % BLKB;
  const float S1 = sqrtf(S2F);

  const float* rowb = rowpts + (size_t)b * NPTS * 3;
  const float* colb = colpts + (size_t)b * NPTS * 3;
  const float* Vi   = Vin  + b * NPTS;
  float*       Vo   = Vout + b * NPTS;

  for (int m = tid; m < NPTS; m += NTHREADS) {
    const float* p = colb + m * 3;
    float y0 = p[0] * S1, y1 = p[1] * S1, y2 = p[2] * S1;
    float w = Vi[m] - (y0 * y0 + y1 * y1 + y2 * y2) + LB2;
    cols4[m] = make_float4(y0, y1, y2, w);
  }
  __syncthreads();

  const int n0 = bib * ROWS_PER_BLOCK + wid * RPW;
  float x2[RPW][3], XX[RPW], S[RPW];
#pragma unroll
  for (int r = 0; r < RPW; ++r) {
    const float* p = rowb + (n0 + r) * 3;
    float a0 = p[0] * S1, a1 = p[1] * S1, a2 = p[2] * S1;
    XX[r] = a0 * a0 + a1 * a1 + a2 * a2;
    x2[r][0] = a0 + a0; x2[r][1] = a1 + a1; x2[r][2] = a2 + a2;
    S[r] = 0.0f;
  }
  for (int ms = 0; ms < MSTEPS; ++ms) {
    float4 v = cols4[ms * 64 + lane];
#pragma unroll
    for (int r = 0; r < RPW; ++r) {
      float t = v.w - XX[r];
      t = fmaf(x2[r][0], v.x, t);
      t = fmaf(x2[r][1], v.y, t);
      t = fmaf(x2[r][2], v.z, t);            // Vin - C2 + LB2
      S[r] += EXP2(t);
    }
  }
#pragma unroll
  for (int r = 0; r < RPW; ++r) {
    float s = S[r];
    for (int off = 32; off; off >>= 1) s += __shfl_xor(s, off);
    if (lane == r) Vo[n0 + r] = -log2f(s);   // plain store, own row
  }
}

// ================= final transport cost =================
// partial[blk] += sum_{n in strip, m} 2^(F+G-C2) * C2   (scaled domain)
__global__ void __launch_bounds__(NTHREADS, 4)
transport_kernel(const float* __restrict__ target,
                 const float* __restrict__ pre,
                 unsigned char* __restrict__ ws)
{
  float* partial = (float*)(ws + WS_PART);
  const float* F = (const float*)(ws + WS_F);
  const float* G = (const float*)(ws + WS_G);

  __shared__ float4 cols4[NPTS];   // {sx, sy, sz, G - yy}
  __shared__ float  Graw[NPTS];
  __shared__ float  wsum[NWAVES];

  const int tid  = threadIdx.x;
  const int wid  = tid >> 6;
  const int lane = tid & 63;
  const int b    = blockIdx.x / BLKB;
  const int bib  = blockIdx.x % BLKB;
  const float S1 = sqrtf(S2F);

  const float* tb = target + (size_t)b * NPTS * 3;
  const float* pb = pre    + (size_t)b * NPTS * 3;
  const float* Fb = F + b * NPTS;
  const float* Gb = G + b * NPTS;

  for (int m = tid; m < NPTS; m += NTHREADS) {
    const float* p = tb + m * 3;
    float y0 = p[0] * S1, y1 = p[1] * S1, y2 = p[2] * S1;
    float g = Gb[m];
    cols4[m] = make_float4(y0, y1, y2, g - (y0 * y0 + y1 * y1 + y2 * y2));
    Graw[m] = g;
  }
  __syncthreads();

  const int n0 = bib * ROWS_PER_BLOCK + wid * RPW;
  float x2[RPW][3], XX[RPW], A2[RPW], Ar[RPW], Sf[RPW];
#pragma unroll
  for (int r = 0; r < RPW; ++r) {
    const float* p = pb + (n0 + r) * 3;
    float a0 = p[0] * S1, a1 = p[1] * S1, a2 = p[2] * S1;
    XX[r] = a0 * a0 + a1 * a1 + a2 * a2;
    x2[r][0] = a0 + a0; x2[r][1] = a1 + a1; x2[r][2] = a2 + a2;
    A2[r] = Fb[n0 + r];
    Ar[r] = A2[r] - XX[r];
    Sf[r] = 0.0f;
  }
  for (int ms = 0; ms < MSTEPS; ++ms) {
    float4 v = cols4[ms * 64 + lane];
    float  g = Graw[ms * 64 + lane];
#pragma unroll
    for (int r = 0; r < RPW; ++r) {
      float u = v.w + Ar[r];                 // F + G - C2
      u = fmaf(x2[r][0], v.x, u);
      u = fmaf(x2[r][1], v.y, u);
      u = fmaf(x2[r][2], v.z, u);
      float e  = EXP2(u);
      float c2 = (A2[r] - u) + g;            // C2 = F + G - u
      Sf[r] = fmaf(e, c2, Sf[r]);
    }
  }
  float tot = 0.0f;
#pragma unroll
  for (int r = 0; r < RPW; ++r) {
    float s = Sf[r];
    for (int off = 32; off; off >>= 1) s += __shfl_xor(s, off);
    tot += s;
  }
  if (lane == 0) wsum[wid] = tot;
  __syncthreads();
  if (tid == 0) {
    float s = 0.0f;
#pragma unroll
    for (int w = 0; w < NWAVES; ++w) s += wsum[w];
    partial[blockIdx.x] += s;                // plain RMW, own slot
  }
}

// ================= final reduce =================
__global__ void __launch_bounds__(NTHREADS, 1)
reduce_kernel(unsigned char* __restrict__ ws, float* __restrict__ out)
{
  const float* partial = (const float*)(ws + WS_PART);
  const float* cmin    = (const float*)(ws + WS_CMIN);
  __shared__ float wsum[NWAVES];

  const int tid  = threadIdx.x;
  const int wid  = tid >> 6;
  const int lane = tid & 63;

  float s = partial[tid];                                  // 512 slots, 1 each
  for (int j = tid; j < BATCH * NPTS; j += NTHREADS)
    s += 0.5f * cmin[j];                                   // d2 terms
  for (int off = 32; off; off >>= 1) s += __shfl_xor(s, off);
  if (lane == 0) wsum[wid] = s;
  __syncthreads();
  if (tid == 0) {
    float t = 0.0f;
#pragma unroll
    for (int w = 0; w < NWAVES; ++w) t += wsum[w];
    // undo scaling: true = scaled / S2 ; then /2048 for per-point means
    out[0] = t * (0.13862943611198906f / 2048.0f);
  }
}

extern "C" void kernel_launch(void* const* d_in, const int* in_sizes, int n_in,
                              void* d_out, int out_size, void* d_ws, size_t ws_size,
                              hipStream_t stream) {
  const float* target = (const float*)d_in[0];
  const float* pre    = (const float*)d_in[1];
  float* out = (float*)d_out;
  unsigned char* ws = (unsigned char*)d_ws;

  float* F = (float*)(ws + WS_F);
  float* G = (float*)(ws + WS_G);

  hipMemsetAsync(ws + WS_F, 0, (size_t)8 * BATCH * NPTS, stream);      // F, G = 0
  hipMemsetAsync(ws + WS_CMIN, 0x7f, (size_t)4 * BATCH * NPTS, stream); // CMIN = big

  chamfer_kernel<<<dim3(NBLOCKS), dim3(NTHREADS), 0, stream>>>(target, pre, ws);

  for (int it = 0; it < SINK_ITERS; ++it) {
    // F-update: rows = pre, cols = target, Vin = G
    sink_pass_kernel<<<dim3(NBLOCKS), dim3(NTHREADS), 0, stream>>>(pre, target, G, F);
    // G-update: rows = target, cols = pre, Vin = F
    sink_pass_kernel<<<dim3(NBLOCKS), dim3(NTHREADS), 0, stream>>>(target, pre, F, G);
  }

  transport_kernel<<<dim3(NBLOCKS), dim3(NTHREADS), 0, stream>>>(target, pre, ws);
  reduce_kernel<<<dim3(1), dim3(NTHREADS), 0, stream>>>(ws, out);
}

// Round 9
// 469.118 us; speedup vs baseline: 7.7983x; 1.9650x over previous
//
#include <hip/hip_runtime.h>
#include <math.h>

#define NTHREADS 512
#define NPTS 2048
#define MSTEPS (NPTS / 64)              // 32
#define RPW 4                           // rows per wave
#define NWAVES (NTHREADS / 64)          // 8
#define ROWS_PER_BLOCK (NWAVES * RPW)   // 32
#define BLKB (NPTS / ROWS_PER_BLOCK)    // 64 blocks per batch
#define BATCH 8
#define NBLOCKS (BATCH * BLKB)          // 512
#define SINK_ITERS 20

#if __has_builtin(__builtin_amdgcn_exp2f)
#define EXP2(x) __builtin_amdgcn_exp2f(x)
#else
#define EXP2(x) exp2f(x)
#endif

// log2-domain scaling: distances scaled by S2F = 1/(EPS*ln2); coords by sqrt(S2F)
#define S2F 7.21347520444482f
#define LB2 -11.0f                      // log2(1/2048)
#define FINAL_SCALE (0.13862943611198906f / 2048.0f)   // (EPS*ln2)/2048

// ---------- workspace layout (bytes) ----------
#define WS_PART  0                                    // float partial[512]
#define WS_DONE  2048                                 // uint done (own line)
#define WS_F     4096                                 // float F[8][2048]
#define WS_G     (WS_F    + 4 * BATCH * NPTS)         // float G[8][2048]
#define WS_CMIN  (WS_G    + 4 * BATCH * NPTS)         // uint  CMIN[8][2048] (+inf init)
#define WS_PT    (WS_CMIN + 4 * BATCH * NPTS)         // float4 PT[8][2048] packed target
#define WS_PP    (WS_PT   + 16 * BATCH * NPTS)        // float4 PP[8][2048] packed pre
// total = 4096 + 3*64KB + 2*128KB = ~452 KB

static __device__ __forceinline__ float aload(const float* p) {
  return __hip_atomic_load(p, __ATOMIC_RELAXED, __HIP_MEMORY_SCOPE_AGENT);
}
static __device__ __forceinline__ unsigned aloadu(const unsigned* p) {
  return __hip_atomic_load(p, __ATOMIC_RELAXED, __HIP_MEMORY_SCOPE_AGENT);
}

// ================= prep: pack/scale points, init F,G,CMIN,done =================
__global__ void __launch_bounds__(256, 4)
prep_kernel(const float* __restrict__ target, const float* __restrict__ pre,
            unsigned char* __restrict__ ws)
{
  float4*   PT   = (float4*)(ws + WS_PT);
  float4*   PP   = (float4*)(ws + WS_PP);
  float*    F    = (float*)(ws + WS_F);
  float*    G    = (float*)(ws + WS_G);
  unsigned* CMIN = (unsigned*)(ws + WS_CMIN);
  unsigned* done = (unsigned*)(ws + WS_DONE);

  const float S1 = sqrtf(S2F);
  int gid = blockIdx.x * 256 + threadIdx.x;           // 16384 threads == BATCH*NPTS
  if (gid == 0) *done = 0u;
  if (gid < BATCH * NPTS) {
    const float* p = target + (size_t)gid * 3;
    float y0 = p[0] * S1, y1 = p[1] * S1, y2 = p[2] * S1;
    PT[gid] = make_float4(y0, y1, y2, y0 * y0 + y1 * y1 + y2 * y2);
    const float* q = pre + (size_t)gid * 3;
    float z0 = q[0] * S1, z1 = q[1] * S1, z2 = q[2] * S1;
    PP[gid] = make_float4(z0, z1, z2, z0 * z0 + z1 * z1 + z2 * z2);
    F[gid] = 0.0f;
    G[gid] = 0.0f;
    CMIN[gid] = 0x7f800000u;                          // +inf
  }
}

// ================= one Sinkhorn half-pass =================
// MODE 0: plain     : Vout[n] = -log2( sum_m 2^( Vin[m] - C2s + LB2 ) )
// MODE 1: first F   : Vin==0 implicit; also chamfer: d1 -> partial, colmin -> CMIN
// MODE 2: last G    : also transport: partial[blk] += 2048*Sc/S per row; last block reduces
template<int MODE>
__global__ void __launch_bounds__(NTHREADS, 4)
sink_kernel(const float4* __restrict__ rowpts, const float4* __restrict__ colpts,
            const float* __restrict__ Vin, float* __restrict__ Vout,
            unsigned char* __restrict__ ws, float* __restrict__ out)
{
  float*    partial = (float*)(ws + WS_PART);
  unsigned* done    = (unsigned*)(ws + WS_DONE);
  unsigned* CMIN    = (unsigned*)(ws + WS_CMIN);

  __shared__ float4 cols4[NPTS];   // {sx, sy, sz, w}          32 KB
  __shared__ float  W2[NPTS];      // MODE1: colmin; MODE2: F+LB2   8 KB
  __shared__ float  wsum[NWAVES];
  __shared__ int    isLast;

  const int tid  = threadIdx.x;
  const int wid  = tid >> 6;
  const int lane = tid & 63;
  const int b    = blockIdx.x / BLKB;
  const int bib  = blockIdx.x % BLKB;

  const float4* rb = rowpts + (size_t)b * NPTS;
  const float4* cb = colpts + (size_t)b * NPTS;
  const float*  Vi = (MODE == 1) ? nullptr : (Vin + (size_t)b * NPTS);
  float*        Vo = (MODE == 2) ? nullptr : (Vout + (size_t)b * NPTS);
  unsigned*     CMb = CMIN + (size_t)b * NPTS;

  // ---- stage columns ----
  for (int m = tid; m < NPTS; m += NTHREADS) {
    float4 p = cb[m];
    float w;
    if (MODE == 1) {
      w = LB2 - p.w;                                  // G=0
      ((unsigned*)W2)[m] = 0x7f800000u;               // colmin = +inf
    } else {
      float v = Vi[m];
      w = v - p.w + LB2;
      if (MODE == 2) W2[m] = v + LB2;                 // F + LB2 (for C2s recovery)
    }
    cols4[m] = make_float4(p.x, p.y, p.z, w);
  }
  __syncthreads();

  // ---- rows ----
  const int n0 = bib * ROWS_PER_BLOCK + wid * RPW;
  float x2[RPW][3], XX[RPW], S[RPW], tm[RPW], Sc[RPW];
#pragma unroll
  for (int r = 0; r < RPW; ++r) {
    float4 a = rb[n0 + r];
    XX[r] = a.w;
    x2[r][0] = a.x + a.x; x2[r][1] = a.y + a.y; x2[r][2] = a.z + a.z;
    S[r] = 0.0f;
    if (MODE == 1) tm[r] = -3.0e38f;
    if (MODE == 2) Sc[r] = 0.0f;
  }

#pragma unroll 2
  for (int ms = 0; ms < MSTEPS; ++ms) {
    float4 v = cols4[ms * 64 + lane];
    float w2;
    if (MODE == 2) w2 = W2[ms * 64 + lane];
    float tmax;
    if (MODE == 1) tmax = -3.0e38f;
#pragma unroll
    for (int r = 0; r < RPW; ++r) {
      float t = v.w - XX[r];
      t = fmaf(x2[r][0], v.x, t);
      t = fmaf(x2[r][1], v.y, t);
      t = fmaf(x2[r][2], v.z, t);            // t = Vin - C2s + LB2
      float e = EXP2(t);
      S[r] += e;
      if (MODE == 1) { tm[r] = fmaxf(tm[r], t); tmax = fmaxf(tmax, t); }
      if (MODE == 2) { Sc[r] = fmaf(e, w2 - t, Sc[r]); }   // += e * C2s
    }
    if (MODE == 1)                            // strip col-min of C2s = LB2 - max t
      atomicMin((unsigned*)&W2[ms * 64 + lane], __float_as_uint(LB2 - tmax));
  }

  // ---- row reductions ----
  float rowacc = 0.0f;
#pragma unroll
  for (int r = 0; r < RPW; ++r) {
    float s = S[r];
    for (int off = 32; off; off >>= 1) s += __shfl_xor(s, off);
    if (MODE != 2) {
      if (lane == r) Vo[n0 + r] = -log2f(s);
    } else {
      float sc = Sc[r];
      for (int off = 32; off; off >>= 1) sc += __shfl_xor(sc, off);
      rowacc += 2048.0f * (sc / s);           // row transport contribution
    }
    if (MODE == 1) {
      float t = tm[r];
      for (int off = 32; off; off >>= 1) t = fmaxf(t, __shfl_xor(t, off));
      rowacc += LB2 - t;                      // dist1 = min_m C2s
    }
  }

  if (MODE == 1) {
    if (lane == 0) wsum[wid] = rowacc;
    __syncthreads();                          // also: W2 colmin complete
    if (tid == 0) {
      float s = 0.0f;
#pragma unroll
      for (int w = 0; w < NWAVES; ++w) s += wsum[w];
      partial[blockIdx.x] = s;
    }
    for (int m = tid; m < NPTS; m += NTHREADS)
      atomicMin(&CMb[m], ((unsigned*)W2)[m]);
  }

  if (MODE == 2) {
    if (lane == 0) wsum[wid] = rowacc;
    __syncthreads();
    if (tid == 0) {
      float s = 0.0f;
#pragma unroll
      for (int w = 0; w < NWAVES; ++w) s += wsum[w];
      partial[blockIdx.x] += s;               // on top of pass-1 d1
      __threadfence();
      unsigned old = __hip_atomic_fetch_add(done, 1u, __ATOMIC_ACQ_REL,
                                            __HIP_MEMORY_SCOPE_AGENT);
      isLast = (old == (unsigned)NBLOCKS - 1u) ? 1 : 0;
    }
    __syncthreads();
    if (isLast) {                             // final reduce in last block
      float s = aload(&partial[tid]);         // 512 slots, cache-bypassing reads
      for (int j = tid; j < BATCH * NPTS; j += NTHREADS)
        s += 0.5f * __uint_as_float(aloadu(&CMIN[j]));     // dist2 terms
      for (int off = 32; off; off >>= 1) s += __shfl_xor(s, off);
      if (lane == 0) wsum[wid] = s;
      __syncthreads();
      if (tid == 0) {
        float t = 0.0f;
#pragma unroll
        for (int w = 0; w < NWAVES; ++w) t += wsum[w];
        out[0] = t * FINAL_SCALE;
      }
    }
  }
}

extern "C" void kernel_launch(void* const* d_in, const int* in_sizes, int n_in,
                              void* d_out, int out_size, void* d_ws, size_t ws_size,
                              hipStream_t stream) {
  const float* target = (const float*)d_in[0];
  const float* pre    = (const float*)d_in[1];
  float* out = (float*)d_out;
  unsigned char* ws = (unsigned char*)d_ws;

  const float4* PT = (const float4*)(ws + WS_PT);
  const float4* PP = (const float4*)(ws + WS_PP);
  float* F = (float*)(ws + WS_F);
  float* G = (float*)(ws + WS_G);

  prep_kernel<<<dim3((BATCH * NPTS + 255) / 256), dim3(256), 0, stream>>>(target, pre, ws);

  // it 0: F-update fused with chamfer (G == 0)
  sink_kernel<1><<<dim3(NBLOCKS), dim3(NTHREADS), 0, stream>>>(PP, PT, nullptr, F, ws, nullptr);
  sink_kernel<0><<<dim3(NBLOCKS), dim3(NTHREADS), 0, stream>>>(PT, PP, F, G, ws, nullptr);

  for (int it = 1; it < SINK_ITERS; ++it) {
    // F-update: rows = pre, cols = target, Vin = G
    sink_kernel<0><<<dim3(NBLOCKS), dim3(NTHREADS), 0, stream>>>(PP, PT, G, F, ws, nullptr);
    if (it < SINK_ITERS - 1) {
      // G-update: rows = target, cols = pre, Vin = F
      sink_kernel<0><<<dim3(NBLOCKS), dim3(NTHREADS), 0, stream>>>(PT, PP, F, G, ws, nullptr);
    } else {
      // last G-update fused with transport cost + final reduce
      sink_kernel<2><<<dim3(NBLOCKS), dim3(NTHREADS), 0, stream>>>(PT, PP, F, nullptr, ws, out);
    }
  }
}

// Round 11
// 460.923 us; speedup vs baseline: 7.9370x; 1.0178x over previous
//
#include <hip/hip_runtime.h>
#include <math.h>

#define NTHREADS 512
#define NPTS 2048
#define MSTEPS (NPTS / 64)              // 32
#define RPW 4                           // rows per wave
#define NWAVES (NTHREADS / 64)          // 8
#define ROWS_PER_BLOCK (NWAVES * RPW)   // 32
#define BLKB (NPTS / ROWS_PER_BLOCK)    // 64 blocks per batch
#define BATCH 8
#define NBLOCKS (BATCH * BLKB)          // 512
#define SINK_ITERS 20

#if __has_builtin(__builtin_amdgcn_exp2f)
#define EXP2(x) __builtin_amdgcn_exp2f(x)
#else
#define EXP2(x) exp2f(x)
#endif

// log2-domain scaling: distances scaled by S2F = 1/(EPS*ln2); coords by sqrt(S2F)
#define S2F 7.21347520444482f
#define LB2 -11.0f                      // log2(1/2048)
#define FINAL_SCALE (0.13862943611198906f / 2048.0f)   // (EPS*ln2)/2048

// ---------- workspace layout (bytes) ----------
#define WS_PART  0                                    // float partial[512]
#define WS_DONE  2048                                 // uint done (own line)
#define WS_F     4096                                 // float F[8][2048]
#define WS_G     (WS_F    + 4 * BATCH * NPTS)         // float G[8][2048]
#define WS_PT    (WS_G    + 4 * BATCH * NPTS)         // float4 PT[8][2048]
#define WS_PP    (WS_PT   + 16 * BATCH * NPTS)        // float4 PP[8][2048]

static __device__ __forceinline__ float aload(const float* p) {
  return __hip_atomic_load(p, __ATOMIC_RELAXED, __HIP_MEMORY_SCOPE_AGENT);
}

// ================= first F-pass: pack points + F-update + chamfer dist1 ========
// G == 0 implicit:  t = LB2 - C2s;  F[n] = -log2(sum 2^t);  dist1 = LB2 - max t.
// Also writes packed strips PT/PP (strip-owned, no redundancy) and done=0.
__global__ void __launch_bounds__(NTHREADS, 4)
sink_first_kernel(const float* __restrict__ target, const float* __restrict__ pre,
                  unsigned char* __restrict__ ws)
{
  float*    partial = (float*)(ws + WS_PART);
  unsigned* done    = (unsigned*)(ws + WS_DONE);
  float*    F       = (float*)(ws + WS_F);
  float4*   PT      = (float4*)(ws + WS_PT);
  float4*   PP      = (float4*)(ws + WS_PP);

  __shared__ float4 cols4[NPTS];   // {sx, sy, sz, LB2 - yy}   32 KB
  __shared__ float  wsum[NWAVES];

  const int tid  = threadIdx.x;
  const int wid  = tid >> 6;
  const int lane = tid & 63;
  const int b    = blockIdx.x / BLKB;
  const int bib  = blockIdx.x % BLKB;
  const float S1 = sqrtf(S2F);

  if (blockIdx.x == 0 && tid == 0) *done = 0u;

  const float*  tb = target + (size_t)b * NPTS * 3;
  const float*  pb = pre    + (size_t)b * NPTS * 3;
  const unsigned mlo = (unsigned)(bib * ROWS_PER_BLOCK);

  // stage all target cols (packed); write own strip of packed PT
  for (int m = tid; m < NPTS; m += NTHREADS) {
    const float* p = tb + m * 3;
    float y0 = p[0] * S1, y1 = p[1] * S1, y2 = p[2] * S1;
    float yy = y0 * y0 + y1 * y1 + y2 * y2;
    if ((unsigned)m - mlo < (unsigned)ROWS_PER_BLOCK)
      PT[(size_t)b * NPTS + m] = make_float4(y0, y1, y2, yy);
    cols4[m] = make_float4(y0, y1, y2, LB2 - yy);
  }

  // rows: pack own 4 pre rows; write own strip of packed PP
  const int n0 = (int)mlo + wid * RPW;
  float x2[RPW][3], XX[RPW], S[RPW], tm[RPW];
#pragma unroll
  for (int r = 0; r < RPW; ++r) {
    const float* q = pb + (size_t)(n0 + r) * 3;
    float a0 = q[0] * S1, a1 = q[1] * S1, a2 = q[2] * S1;
    float xx = a0 * a0 + a1 * a1 + a2 * a2;
    if (lane == r) PP[(size_t)b * NPTS + n0 + r] = make_float4(a0, a1, a2, xx);
    XX[r] = xx;
    x2[r][0] = a0 + a0; x2[r][1] = a1 + a1; x2[r][2] = a2 + a2;
    S[r] = 0.0f; tm[r] = -3.0e38f;
  }
  __syncthreads();

#pragma unroll 2
  for (int ms = 0; ms < MSTEPS; ++ms) {
    float4 v = cols4[ms * 64 + lane];
#pragma unroll
    for (int r = 0; r < RPW; ++r) {
      float t = v.w - XX[r];
      t = fmaf(x2[r][0], v.x, t);
      t = fmaf(x2[r][1], v.y, t);
      t = fmaf(x2[r][2], v.z, t);            // t = LB2 - C2s
      S[r] += EXP2(t);
      tm[r] = fmaxf(tm[r], t);
    }
  }

  float rowacc = 0.0f;
  float* Fb = F + (size_t)b * NPTS;
#pragma unroll
  for (int r = 0; r < RPW; ++r) {
    float s = S[r];
    for (int off = 32; off; off >>= 1) s += __shfl_xor(s, off);
    if (lane == r) Fb[n0 + r] = -log2f(s);
    float t = tm[r];
    for (int off = 32; off; off >>= 1) t = fmaxf(t, __shfl_xor(t, off));
    rowacc += LB2 - t;                       // dist1 = min C2s (weight 1.0)
  }
  if (lane == 0) wsum[wid] = rowacc;
  __syncthreads();
  if (tid == 0) {
    float s = 0.0f;
#pragma unroll
    for (int w = 0; w < NWAVES; ++w) s += wsum[w];
    partial[blockIdx.x] = s;
  }
}

// ================= Sinkhorn half-pass =================
// MODE 0: plain  : Vout[n] = -log2( sum_m 2^( Vin[m] - C2s + LB2 ) )
// MODE 2: last G : + transport (2048*Sc/S per row) + chamfer dist2 (row-min C2s);
//                  last block reduces partial[] -> out.
template<int MODE>
__global__ void __launch_bounds__(NTHREADS, 4)
sink_kernel(const float4* __restrict__ rowpts, const float4* __restrict__ colpts,
            const float* __restrict__ Vin, float* __restrict__ Vout,
            unsigned char* __restrict__ ws, float* __restrict__ out)
{
  float*    partial = (float*)(ws + WS_PART);
  unsigned* done    = (unsigned*)(ws + WS_DONE);

  __shared__ float4 cols4[NPTS];   // {sx, sy, sz, Vin - yy + LB2}   32 KB
  __shared__ float  W2[MODE == 2 ? NPTS : 1];   // MODE2: Vin + LB2
  __shared__ float  wsum[NWAVES];
  __shared__ int    isLast;

  const int tid  = threadIdx.x;
  const int wid  = tid >> 6;
  const int lane = tid & 63;
  const int b    = blockIdx.x / BLKB;
  const int bib  = blockIdx.x % BLKB;

  const float4* rb = rowpts + (size_t)b * NPTS;
  const float4* cb = colpts + (size_t)b * NPTS;
  const float*  Vi = Vin + (size_t)b * NPTS;
  float*        Vo = (MODE == 2) ? nullptr : (Vout + (size_t)b * NPTS);

  for (int m = tid; m < NPTS; m += NTHREADS) {
    float4 p = cb[m];
    float v = Vi[m];
    if (MODE == 2) W2[m] = v + LB2;
    cols4[m] = make_float4(p.x, p.y, p.z, v - p.w + LB2);
  }
  __syncthreads();

  const int n0 = bib * ROWS_PER_BLOCK + wid * RPW;
  float x2[RPW][3], XX[RPW], S[RPW], Sc[RPW], rm2[RPW];
#pragma unroll
  for (int r = 0; r < RPW; ++r) {
    float4 a = rb[n0 + r];
    XX[r] = a.w;
    x2[r][0] = a.x + a.x; x2[r][1] = a.y + a.y; x2[r][2] = a.z + a.z;
    S[r] = 0.0f;
    if (MODE == 2) { Sc[r] = 0.0f; rm2[r] = 3.0e38f; }
  }

#pragma unroll 2
  for (int ms = 0; ms < MSTEPS; ++ms) {
    float4 v = cols4[ms * 64 + lane];
    float w2;
    if (MODE == 2) w2 = W2[ms * 64 + lane];
#pragma unroll
    for (int r = 0; r < RPW; ++r) {
      float t = v.w - XX[r];
      t = fmaf(x2[r][0], v.x, t);
      t = fmaf(x2[r][1], v.y, t);
      t = fmaf(x2[r][2], v.z, t);            // t = Vin - C2s + LB2
      float e = EXP2(t);
      S[r] += e;
      if (MODE == 2) {
        float c2 = w2 - t;                   // = C2s
        Sc[r] = fmaf(e, c2, Sc[r]);
        rm2[r] = fminf(rm2[r], c2);
      }
    }
  }

  float rowacc = 0.0f;
#pragma unroll
  for (int r = 0; r < RPW; ++r) {
    float s = S[r];
    for (int off = 32; off; off >>= 1) s += __shfl_xor(s, off);
    if (MODE != 2) {
      if (lane == r) Vo[n0 + r] = -log2f(s);
    } else {
      float sc = Sc[r];
      for (int off = 32; off; off >>= 1) sc += __shfl_xor(sc, off);
      float m2 = rm2[r];
      for (int off = 32; off; off >>= 1) m2 = fminf(m2, __shfl_xor(m2, off));
      rowacc += 2048.0f * (sc / s) + 0.5f * m2;   // transport + dist2
    }
  }

  if (MODE == 2) {
    if (lane == 0) wsum[wid] = rowacc;
    __syncthreads();
    if (tid == 0) {
      float s = 0.0f;
#pragma unroll
      for (int w = 0; w < NWAVES; ++w) s += wsum[w];
      partial[blockIdx.x] += s;              // on top of pass-1 d1
      __threadfence();
      unsigned old = __hip_atomic_fetch_add(done, 1u, __ATOMIC_ACQ_REL,
                                            __HIP_MEMORY_SCOPE_AGENT);
      isLast = (old == (unsigned)NBLOCKS - 1u) ? 1 : 0;
    }
    __syncthreads();
    if (isLast) {                            // final reduce in last block
      float s = aload(&partial[tid]);        // 512 slots, one per thread
      for (int off = 32; off; off >>= 1) s += __shfl_xor(s, off);
      if (lane == 0) wsum[wid] = s;
      __syncthreads();
      if (tid == 0) {
        float t = 0.0f;
#pragma unroll
        for (int w = 0; w < NWAVES; ++w) t += wsum[w];
        out[0] = t * FINAL_SCALE;
      }
    }
  }
}

extern "C" void kernel_launch(void* const* d_in, const int* in_sizes, int n_in,
                              void* d_out, int out_size, void* d_ws, size_t ws_size,
                              hipStream_t stream) {
  const float* target = (const float*)d_in[0];
  const float* pre    = (const float*)d_in[1];
  float* out = (float*)d_out;
  unsigned char* ws = (unsigned char*)d_ws;

  const float4* PT = (const float4*)(ws + WS_PT);
  const float4* PP = (const float4*)(ws + WS_PP);
  float* F = (float*)(ws + WS_F);
  float* G = (float*)(ws + WS_G);

  // it 0: F-update fused with packing + chamfer dist1 (G == 0)
  sink_first_kernel<<<dim3(NBLOCKS), dim3(NTHREADS), 0, stream>>>(target, pre, ws);
  // it 0: G-update
  sink_kernel<0><<<dim3(NBLOCKS), dim3(NTHREADS), 0, stream>>>(PT, PP, F, G, ws, nullptr);

  for (int it = 1; it < SINK_ITERS; ++it) {
    // F-update: rows = pre, cols = target, Vin = G
    sink_kernel<0><<<dim3(NBLOCKS), dim3(NTHREADS), 0, stream>>>(PP, PT, G, F, ws, nullptr);
    if (it < SINK_ITERS - 1) {
      // G-update: rows = target, cols = pre, Vin = F
      sink_kernel<0><<<dim3(NBLOCKS), dim3(NTHREADS), 0, stream>>>(PT, PP, F, G, ws, nullptr);
    } else {
      // last G-update fused with transport + chamfer dist2 + final reduce
      sink_kernel<2><<<dim3(NBLOCKS), dim3(NTHREADS), 0, stream>>>(PT, PP, F, nullptr, ws, out);
    }
  }
}

// Round 13
// 428.229 us; speedup vs baseline: 8.5429x; 1.0763x over previous
//
#include <hip/hip_runtime.h>
#include <math.h>

#define NTHREADS 512
#define NPTS 2048
#define MSTEPS (NPTS / 64)              // 32 (scalar paths)
#define MSTEPS2 (NPTS / 128)            // 16 (packed path: 2 cols/lane/step)
#define RPW 4                           // rows per wave
#define NWAVES (NTHREADS / 64)          // 8
#define ROWS_PER_BLOCK (NWAVES * RPW)   // 32
#define BLKB (NPTS / ROWS_PER_BLOCK)    // 64 blocks per batch
#define BATCH 8
#define NBLOCKS (BATCH * BLKB)          // 512
#define SINK_ITERS 20

#if __has_builtin(__builtin_amdgcn_exp2f)
#define EXP2(x) __builtin_amdgcn_exp2f(x)
#else
#define EXP2(x) exp2f(x)
#endif

// log2-domain scaling: distances scaled by S2F = 1/(EPS*ln2); coords by sqrt(S2F)
#define S2F 7.21347520444482f
#define LB2 -11.0f                      // log2(1/2048)
#define FINAL_SCALE (0.13862943611198906f / 2048.0f)   // (EPS*ln2)/2048

// ---------- workspace layout (bytes) ----------
#define WS_PART  0                                    // float partial[512]
#define WS_DONE  2048                                 // uint done (own line)
#define WS_F     4096                                 // float F[8][2048]
#define WS_G     (WS_F    + 4 * BATCH * NPTS)         // float G[8][2048]
#define WS_PT    (WS_G    + 4 * BATCH * NPTS)         // float4 PT[8][2048]
#define WS_PP    (WS_PT   + 16 * BATCH * NPTS)        // float4 PP[8][2048]

static __device__ __forceinline__ float aload(const float* p) {
  return __hip_atomic_load(p, __ATOMIC_RELAXED, __HIP_MEMORY_SCOPE_AGENT);
}

// ================= first F-pass: pack points + F-update + chamfer dist1 ========
// G == 0 implicit:  t = LB2 - C2s;  F[n] = -log2(sum 2^t);  dist1 = LB2 - max t.
// Also writes packed strips PT/PP (strip-owned, no redundancy) and done=0.
__global__ void __launch_bounds__(NTHREADS, 4)
sink_first_kernel(const float* __restrict__ target, const float* __restrict__ pre,
                  unsigned char* __restrict__ ws)
{
  float*    partial = (float*)(ws + WS_PART);
  unsigned* done    = (unsigned*)(ws + WS_DONE);
  float*    F       = (float*)(ws + WS_F);
  float4*   PT      = (float4*)(ws + WS_PT);
  float4*   PP      = (float4*)(ws + WS_PP);

  __shared__ float4 cols4[NPTS];   // {sx, sy, sz, LB2 - yy}   32 KB
  __shared__ float  wsum[NWAVES];

  const int tid  = threadIdx.x;
  const int wid  = tid >> 6;
  const int lane = tid & 63;
  const int b    = blockIdx.x / BLKB;
  const int bib  = blockIdx.x % BLKB;
  const float S1 = sqrtf(S2F);

  if (blockIdx.x == 0 && tid == 0) *done = 0u;

  const float*  tb = target + (size_t)b * NPTS * 3;
  const float*  pb = pre    + (size_t)b * NPTS * 3;
  const unsigned mlo = (unsigned)(bib * ROWS_PER_BLOCK);

  // stage all target cols (packed); write own strip of packed PT
  for (int m = tid; m < NPTS; m += NTHREADS) {
    const float* p = tb + m * 3;
    float y0 = p[0] * S1, y1 = p[1] * S1, y2 = p[2] * S1;
    float yy = y0 * y0 + y1 * y1 + y2 * y2;
    if ((unsigned)m - mlo < (unsigned)ROWS_PER_BLOCK)
      PT[(size_t)b * NPTS + m] = make_float4(y0, y1, y2, yy);
    cols4[m] = make_float4(y0, y1, y2, LB2 - yy);
  }

  // rows: pack own 4 pre rows; write own strip of packed PP
  const int n0 = (int)mlo + wid * RPW;
  float x2[RPW][3], XX[RPW], S[RPW], tm[RPW];
#pragma unroll
  for (int r = 0; r < RPW; ++r) {
    const float* q = pb + (size_t)(n0 + r) * 3;
    float a0 = q[0] * S1, a1 = q[1] * S1, a2 = q[2] * S1;
    float xx = a0 * a0 + a1 * a1 + a2 * a2;
    if (lane == r) PP[(size_t)b * NPTS + n0 + r] = make_float4(a0, a1, a2, xx);
    XX[r] = xx;
    x2[r][0] = a0 + a0; x2[r][1] = a1 + a1; x2[r][2] = a2 + a2;
    S[r] = 0.0f; tm[r] = -3.0e38f;
  }
  __syncthreads();

#pragma unroll 2
  for (int ms = 0; ms < MSTEPS; ++ms) {
    float4 v = cols4[ms * 64 + lane];
#pragma unroll
    for (int r = 0; r < RPW; ++r) {
      float t = v.w - XX[r];
      t = fmaf(x2[r][0], v.x, t);
      t = fmaf(x2[r][1], v.y, t);
      t = fmaf(x2[r][2], v.z, t);            // t = LB2 - C2s
      S[r] += EXP2(t);
      tm[r] = fmaxf(tm[r], t);
    }
  }

  float rowacc = 0.0f;
  float* Fb = F + (size_t)b * NPTS;
#pragma unroll
  for (int r = 0; r < RPW; ++r) {
    float s = S[r];
    for (int off = 32; off; off >>= 1) s += __shfl_xor(s, off);
    if (lane == r) Fb[n0 + r] = -log2f(s);
    float t = tm[r];
    for (int off = 32; off; off >>= 1) t = fmaxf(t, __shfl_xor(t, off));
    rowacc += LB2 - t;                       // dist1 = min C2s (weight 1.0)
  }
  if (lane == 0) wsum[wid] = rowacc;
  __syncthreads();
  if (tid == 0) {
    float s = 0.0f;
#pragma unroll
    for (int w = 0; w < NWAVES; ++w) s += wsum[w];
    partial[blockIdx.x] = s;
  }
}

// ================= Sinkhorn half-pass =================
// MODE 0: plain  : Vout[n] = -log2( sum_m 2^( Vin[m] - C2s + LB2 ) )
//                  packed-fp32 inner loop (v_pk_fma_f32, 2 cols/lane/step)
// MODE 2: last G : + transport (2048*Sc/S per row) + chamfer dist2 (row-min C2s);
//                  last block reduces partial[] -> out. (scalar loop, 1 node)
template<int MODE>
__global__ void __launch_bounds__(NTHREADS, 4)
sink_kernel(const float4* __restrict__ rowpts, const float4* __restrict__ colpts,
            const float* __restrict__ Vin, float* __restrict__ Vout,
            unsigned char* __restrict__ ws, float* __restrict__ out)
{
  float*    partial = (float*)(ws + WS_PART);
  unsigned* done    = (unsigned*)(ws + WS_DONE);

  // SoA column store: float2 loads = stride-8B = free 2-way bank aliasing
  __shared__ __align__(16) float colx[NPTS];
  __shared__ __align__(16) float coly[NPTS];
  __shared__ __align__(16) float colz[NPTS];
  __shared__ __align__(16) float colw[NPTS];   // Vin - yy + LB2
  __shared__ float  W2[MODE == 2 ? NPTS : 1];  // MODE2: Vin + LB2
  __shared__ float  wsum[NWAVES];
  __shared__ int    isLast;

  const int tid  = threadIdx.x;
  const int wid  = tid >> 6;
  const int lane = tid & 63;
  const int b    = blockIdx.x / BLKB;
  const int bib  = blockIdx.x % BLKB;

  const float4* rb = rowpts + (size_t)b * NPTS;
  const float4* cb = colpts + (size_t)b * NPTS;
  const float*  Vi = Vin + (size_t)b * NPTS;
  float*        Vo = (MODE == 2) ? nullptr : (Vout + (size_t)b * NPTS);

  for (int m = tid; m < NPTS; m += NTHREADS) {
    float4 p = cb[m];
    float v = Vi[m];
    colx[m] = p.x; coly[m] = p.y; colz[m] = p.z;
    colw[m] = v - p.w + LB2;
    if (MODE == 2) W2[m] = v + LB2;
  }
  __syncthreads();

  const int n0 = bib * ROWS_PER_BLOCK + wid * RPW;
  float rowacc = 0.0f;

  if (MODE == 0) {
    // ---- packed path: row constants pre-broadcast into float2 pairs ----
    float2 XXn2[RPW], X2x[RPW], X2y[RPW], X2z[RPW];
    float  Sa[RPW], Sb[RPW];
#pragma unroll
    for (int r = 0; r < RPW; ++r) {
      float4 a = rb[n0 + r];
      XXn2[r] = make_float2(-a.w, -a.w);
      X2x[r]  = make_float2(a.x + a.x, a.x + a.x);
      X2y[r]  = make_float2(a.y + a.y, a.y + a.y);
      X2z[r]  = make_float2(a.z + a.z, a.z + a.z);
      Sa[r] = 0.0f; Sb[r] = 0.0f;
    }
    const float2* cx = (const float2*)colx;
    const float2* cy = (const float2*)coly;
    const float2* cz = (const float2*)colz;
    const float2* cw = (const float2*)colw;

#pragma unroll 2
    for (int ms = 0; ms < MSTEPS2; ++ms) {
      const int idx = ms * 64 + lane;
      float2 vx = cx[idx], vy = cy[idx], vz = cz[idx], vw = cw[idx];
#pragma unroll
      for (int r = 0; r < RPW; ++r) {
        float2 t;
        asm("v_pk_add_f32 %0, %1, %2"     : "=v"(t) : "v"(vw), "v"(XXn2[r]));
        asm("v_pk_fma_f32 %0, %1, %2, %3" : "=v"(t) : "v"(vx), "v"(X2x[r]), "v"(t));
        asm("v_pk_fma_f32 %0, %1, %2, %3" : "=v"(t) : "v"(vy), "v"(X2y[r]), "v"(t));
        asm("v_pk_fma_f32 %0, %1, %2, %3" : "=v"(t) : "v"(vz), "v"(X2z[r]), "v"(t));
        Sa[r] += EXP2(t.x);                 // t = Vin - C2s + LB2 (per column half)
        Sb[r] += EXP2(t.y);
      }
    }
#pragma unroll
    for (int r = 0; r < RPW; ++r) {
      float s = Sa[r] + Sb[r];
      for (int off = 32; off; off >>= 1) s += __shfl_xor(s, off);
      if (lane == r) Vo[n0 + r] = -log2f(s);
    }
  } else {
    // ---- MODE 2 scalar path (one node) ----
    float x2[RPW][3], XX[RPW], S[RPW], Sc[RPW], rm2[RPW];
#pragma unroll
    for (int r = 0; r < RPW; ++r) {
      float4 a = rb[n0 + r];
      XX[r] = a.w;
      x2[r][0] = a.x + a.x; x2[r][1] = a.y + a.y; x2[r][2] = a.z + a.z;
      S[r] = 0.0f; Sc[r] = 0.0f; rm2[r] = 3.0e38f;
    }
#pragma unroll 2
    for (int ms = 0; ms < MSTEPS; ++ms) {
      const int i = ms * 64 + lane;
      float px = colx[i], py = coly[i], pz = colz[i], pw = colw[i];
      float w2 = W2[i];
#pragma unroll
      for (int r = 0; r < RPW; ++r) {
        float t = pw - XX[r];
        t = fmaf(x2[r][0], px, t);
        t = fmaf(x2[r][1], py, t);
        t = fmaf(x2[r][2], pz, t);           // t = Vin - C2s + LB2
        float e = EXP2(t);
        S[r] += e;
        float c2 = w2 - t;                   // = C2s
        Sc[r] = fmaf(e, c2, Sc[r]);
        rm2[r] = fminf(rm2[r], c2);
      }
    }
#pragma unroll
    for (int r = 0; r < RPW; ++r) {
      float s = S[r];
      for (int off = 32; off; off >>= 1) s += __shfl_xor(s, off);
      float sc = Sc[r];
      for (int off = 32; off; off >>= 1) sc += __shfl_xor(sc, off);
      float m2 = rm2[r];
      for (int off = 32; off; off >>= 1) m2 = fminf(m2, __shfl_xor(m2, off));
      rowacc += 2048.0f * (sc / s) + 0.5f * m2;   // transport + dist2
    }
  }

  if (MODE == 2) {
    if (lane == 0) wsum[wid] = rowacc;
    __syncthreads();
    if (tid == 0) {
      float s = 0.0f;
#pragma unroll
      for (int w = 0; w < NWAVES; ++w) s += wsum[w];
      partial[blockIdx.x] += s;              // on top of pass-1 d1
      __threadfence();
      unsigned old = __hip_atomic_fetch_add(done, 1u, __ATOMIC_ACQ_REL,
                                            __HIP_MEMORY_SCOPE_AGENT);
      isLast = (old == (unsigned)NBLOCKS - 1u) ? 1 : 0;
    }
    __syncthreads();
    if (isLast) {                            // final reduce in last block
      float s = aload(&partial[tid]);        // 512 slots, one per thread
      for (int off = 32; off; off >>= 1) s += __shfl_xor(s, off);
      if (lane == 0) wsum[wid] = s;
      __syncthreads();
      if (tid == 0) {
        float t = 0.0f;
#pragma unroll
        for (int w = 0; w < NWAVES; ++w) t += wsum[w];
        out[0] = t * FINAL_SCALE;
      }
    }
  }
}

extern "C" void kernel_launch(void* const* d_in, const int* in_sizes, int n_in,
                              void* d_out, int out_size, void* d_ws, size_t ws_size,
                              hipStream_t stream) {
  const float* target = (const float*)d_in[0];
  const float* pre    = (const float*)d_in[1];
  float* out = (float*)d_out;
  unsigned char* ws = (unsigned char*)d_ws;

  const float4* PT = (const float4*)(ws + WS_PT);
  const float4* PP = (const float4*)(ws + WS_PP);
  float* F = (float*)(ws + WS_F);
  float* G = (float*)(ws + WS_G);

  // it 0: F-update fused with packing + chamfer dist1 (G == 0)
  sink_first_kernel<<<dim3(NBLOCKS), dim3(NTHREADS), 0, stream>>>(target, pre, ws);
  // it 0: G-update
  sink_kernel<0><<<dim3(NBLOCKS), dim3(NTHREADS), 0, stream>>>(PT, PP, F, G, ws, nullptr);

  for (int it = 1; it < SINK_ITERS; ++it) {
    // F-update: rows = pre, cols = target, Vin = G
    sink_kernel<0><<<dim3(NBLOCKS), dim3(NTHREADS), 0, stream>>>(PP, PT, G, F, ws, nullptr);
    if (it < SINK_ITERS - 1) {
      // G-update: rows = target, cols = pre, Vin = F
      sink_kernel<0><<<dim3(NBLOCKS), dim3(NTHREADS), 0, stream>>>(PT, PP, F, G, ws, nullptr);
    } else {
      // last G-update fused with transport + chamfer dist2 + final reduce
      sink_kernel<2><<<dim3(NBLOCKS), dim3(NTHREADS), 0, stream>>>(PT, PP, F, nullptr, ws, out);
    }
  }
}